// Round 7
// baseline (960.186 us; speedup 1.0000x reference)
//
#include <hip/hip_runtime.h>

// RelationNet: B=16, N=16, K=8, H=128, 2H=256
// out[b,n1,o] = mean over (n2,k1,k2) of relu(W3 relu(W2 relu(A[b,n1,k1]+Bv[b,n2,k2])))
// A = enc @ W1[:, :128]^T, Bv = enc @ W1[:, 128:]^T  (layer 1 factors).
// Numerics (validated R5, absmax 3.9e-3 passed): W 2-term fp16 split,
//   y = fp16(x)*(Wh+Wl), 2 MFMAs per product.
// R6 structure: block=(b,n1,n2-half), 512 thr (8 waves = 4 colslice x 2 rowhalf),
//   8 n2-iterations/block with double-buffered LDS -> 8x W reuse per block,
//   build(i+1) overlapped with L3(i).

typedef _Float16 f16;
typedef __attribute__((ext_vector_type(4))) _Float16 f16x4;
typedef __attribute__((ext_vector_type(8))) _Float16 f16x8;
typedef __attribute__((ext_vector_type(4))) float    f32x4;

#define STRH 264   // LDS row stride in fp16: 528B = 132 dw == 4 mod 32 banks
                   // -> A-frag ds_read_b128 (16 lr x 4 lg) is conflict-free

// ws layout in floats:
//   [0)        W1aT  128*256 = 32768   fp32
//   [32768)    W1bT  128*256 = 32768   fp32
//   [65536)    W2h   256*256 fp16  (native [o][k] = MFMA B fragment)
//   [98304)    W2l   256*256 fp16
//   [131072)   W3h   256*256 fp16
//   [163840)   W3l   256*256 fp16
//   [196608)   A1    2048*256 fp32
//   [720896)   B1    2048*256 fp32
//   [1245184)  partial 4096*256 fp32
// total 2293760 floats = 8.75 MB

__global__ void prep_w(const float* __restrict__ W1,
                       const float* __restrict__ W2,
                       const float* __restrict__ W3,
                       float* __restrict__ ws) {
    int e = blockIdx.x * 256 + threadIdx.x;   // 0..65535
    int hi = e >> 8;
    int o  = e & 255;
    if (e < 32768) {
        ws[e]         = W1[o * 256 + hi];        // W1aT[h][o]
        ws[32768 + e] = W1[o * 256 + 128 + hi];  // W1bT[h][o]
    }
    f16* W2h = (f16*)(ws + 65536);
    f16* W2l = (f16*)(ws + 98304);
    f16* W3h = (f16*)(ws + 131072);
    f16* W3l = (f16*)(ws + 163840);
    float w2 = W2[e];
    f16 h2 = (f16)w2;
    W2h[e] = h2;
    W2l[e] = (f16)(w2 - (float)h2);
    float w3 = W3[e];
    f16 h3 = (f16)w3;
    W3h[e] = h3;
    W3l[e] = (f16)(w3 - (float)h3);
}

__global__ void prep_ab(const float* __restrict__ enc,
                        const float* __restrict__ ws,
                        float* __restrict__ A1,
                        float* __restrict__ B1) {
    __shared__ float es[128];
    int row = blockIdx.x;       // 0..2047 = (b*16+n)*8+k
    int o = threadIdx.x;        // 0..255
    if (o < 128) es[o] = enc[row * 128 + o];
    __syncthreads();
    const float* __restrict__ W1aT = ws;
    const float* __restrict__ W1bT = ws + 32768;
    float a = 0.f, bv = 0.f;
#pragma unroll 8
    for (int h = 0; h < 128; ++h) {
        float ev = es[h];
        a  += ev * W1aT[h * 256 + o];
        bv += ev * W1bT[h * 256 + o];
    }
    A1[row * 256 + o] = a;
    B1[row * 256 + o] = bv;
}

__global__ __launch_bounds__(512, 4)
void relnet_main(const float* __restrict__ A1, const float* __restrict__ B1,
                 const f16* __restrict__ W2h, const f16* __restrict__ W2l,
                 const f16* __restrict__ W3h, const f16* __restrict__ W3l,
                 float* __restrict__ partial) {
    __shared__ alignas(16) f16   oh[2][64][STRH];  // 66 KB double buffer
    __shared__ alignas(16) float A_lds[8][256];    // 8 KB (n1-constant)
    __shared__ float po_lds[8][64];                // 2 KB rowhalf-combine

    const int n2h = blockIdx.x, n1 = blockIdx.y, b = blockIdx.z;
    const int tid  = threadIdx.x;
    const int lane = tid & 63;
    const int w    = tid >> 6;       // wave 0..7
    const int lr   = lane & 15;      // frag row/col index
    const int lg   = lane >> 4;      // k-group (A/B) / row-group (D)
    const int ko   = lg * 8;
    const int cslice = w & 3;        // 64-col slice
    const int rhalf  = w >> 2;       // 32-row half
    const int cb     = cslice * 64;
    const int rbase  = rhalf * 32;

    const int bn1 = b * 16 + n1;

    // ---- prologue: stage A (8x256 f32), load Bv(0), build o1(0) -> buf0 ----
    {
        // A: thread t stages one float4
        int ar = tid >> 6, ac = (tid & 63) * 4;
        *(float4*)&A_lds[ar][ac] =
            *(const float4*)&A1[(bn1 * 8 + ar) * 256 + ac];
    }
    // Bv(0): wave w holds k2=w, lane's 4 cols
    float4 bvn = *(const float4*)&B1[((b * 16 + n2h * 8) * 8 + w) * 256 + lane * 4];
    __syncthreads();   // A_lds ready

    // build o1(0) into buf 0
#pragma unroll
    for (int k1 = 0; k1 < 8; ++k1) {
        float4 av = *(const float4*)&A_lds[k1][lane * 4];
        f16x4 hv;
        hv[0] = (f16)fmaxf(av.x + bvn.x, 0.f);
        hv[1] = (f16)fmaxf(av.y + bvn.y, 0.f);
        hv[2] = (f16)fmaxf(av.z + bvn.z, 0.f);
        hv[3] = (f16)fmaxf(av.w + bvn.w, 0.f);
        *(f16x4*)&oh[0][k1 * 8 + w][lane * 4] = hv;
    }

    f32x4 acc[2][4];

#pragma unroll 1
    for (int i = 0; i < 8; ++i) {
        const int cur = i & 1, nxt = cur ^ 1;
        const int n2 = n2h * 8 + i;

        __syncthreads();   // o1(i) in buf[cur] ready; po_lds(i-1) consumed

        // issue Bv(i+1) early (hidden under layer-2 MFMA)
        if (i < 7)
            bvn = *(const float4*)&B1[((b * 16 + n2h * 8 + i + 1) * 8 + w) * 256 + lane * 4];

        // ================= layer 2: read buf[cur], W2 =================
#pragma unroll
        for (int fm = 0; fm < 2; ++fm)
#pragma unroll
            for (int fn = 0; fn < 4; ++fn) acc[fm][fn] = (f32x4){0.f, 0.f, 0.f, 0.f};

#pragma unroll
        for (int ks = 0; ks < 8; ++ks) {
            f16x8 a0 = *(const f16x8*)&oh[cur][rbase + lr][ks * 32 + ko];
            f16x8 a1 = *(const f16x8*)&oh[cur][rbase + 16 + lr][ks * 32 + ko];
#pragma unroll
            for (int fn = 0; fn < 4; ++fn) {
                const int col = cb + fn * 16 + lr;
                f16x8 bh = *(const f16x8*)&W2h[col * 256 + ks * 32 + ko];
                f16x8 bl = *(const f16x8*)&W2l[col * 256 + ks * 32 + ko];
                acc[0][fn] = __builtin_amdgcn_mfma_f32_16x16x32_f16(a0, bh, acc[0][fn], 0, 0, 0);
                acc[1][fn] = __builtin_amdgcn_mfma_f32_16x16x32_f16(a1, bh, acc[1][fn], 0, 0, 0);
                acc[0][fn] = __builtin_amdgcn_mfma_f32_16x16x32_f16(a0, bl, acc[0][fn], 0, 0, 0);
                acc[1][fn] = __builtin_amdgcn_mfma_f32_16x16x32_f16(a1, bl, acc[1][fn], 0, 0, 0);
            }
        }
        __syncthreads();   // buf[cur] reads done

        // ---- o2 = fp16(relu(acc)) -> buf[cur] (overwrite o1) ----
#pragma unroll
        for (int fm = 0; fm < 2; ++fm)
#pragma unroll
            for (int fn = 0; fn < 4; ++fn)
#pragma unroll
                for (int j = 0; j < 4; ++j) {
                    float v = fmaxf(acc[fm][fn][j], 0.f);
                    oh[cur][rbase + fm * 16 + lg * 4 + j][cb + fn * 16 + lr] = (f16)v;
                }

        // ---- build o1(i+1) -> buf[nxt] (overlaps; reads done last iter) ----
        if (i < 7) {
#pragma unroll
            for (int k1 = 0; k1 < 8; ++k1) {
                float4 av = *(const float4*)&A_lds[k1][lane * 4];
                f16x4 hv;
                hv[0] = (f16)fmaxf(av.x + bvn.x, 0.f);
                hv[1] = (f16)fmaxf(av.y + bvn.y, 0.f);
                hv[2] = (f16)fmaxf(av.z + bvn.z, 0.f);
                hv[3] = (f16)fmaxf(av.w + bvn.w, 0.f);
                *(f16x4*)&oh[nxt][k1 * 8 + w][lane * 4] = hv;
            }
        }
        __syncthreads();   // o2 ready in buf[cur]

        // ================= layer 3: read buf[cur], W3 =================
#pragma unroll
        for (int fm = 0; fm < 2; ++fm)
#pragma unroll
            for (int fn = 0; fn < 4; ++fn) acc[fm][fn] = (f32x4){0.f, 0.f, 0.f, 0.f};

#pragma unroll
        for (int ks = 0; ks < 8; ++ks) {
            f16x8 a0 = *(const f16x8*)&oh[cur][rbase + lr][ks * 32 + ko];
            f16x8 a1 = *(const f16x8*)&oh[cur][rbase + 16 + lr][ks * 32 + ko];
#pragma unroll
            for (int fn = 0; fn < 4; ++fn) {
                const int col = cb + fn * 16 + lr;
                f16x8 bh = *(const f16x8*)&W3h[col * 256 + ks * 32 + ko];
                f16x8 bl = *(const f16x8*)&W3l[col * 256 + ks * 32 + ko];
                acc[0][fn] = __builtin_amdgcn_mfma_f32_16x16x32_f16(a0, bh, acc[0][fn], 0, 0, 0);
                acc[1][fn] = __builtin_amdgcn_mfma_f32_16x16x32_f16(a1, bh, acc[1][fn], 0, 0, 0);
                acc[0][fn] = __builtin_amdgcn_mfma_f32_16x16x32_f16(a0, bl, acc[0][fn], 0, 0, 0);
                acc[1][fn] = __builtin_amdgcn_mfma_f32_16x16x32_f16(a1, bl, acc[1][fn], 0, 0, 0);
            }
        }

        // ---- relu + row-sum over this wave's 32 rows ----
        float po[4] = {0.f, 0.f, 0.f, 0.f};
#pragma unroll
        for (int fn = 0; fn < 4; ++fn)
#pragma unroll
            for (int fm = 0; fm < 2; ++fm)
#pragma unroll
                for (int j = 0; j < 4; ++j)
                    po[fn] += fmaxf(acc[fm][fn][j], 0.f);
#pragma unroll
        for (int fn = 0; fn < 4; ++fn) {
            po[fn] += __shfl_xor(po[fn], 16);
            po[fn] += __shfl_xor(po[fn], 32);
        }
        if (lane < 16) {
#pragma unroll
            for (int fn = 0; fn < 4; ++fn)
                po_lds[w][fn * 16 + lane] = po[fn];
        }
        __syncthreads();   // po_lds ready (also covers buf[cur] L3 reads)

        // ---- combine rowhalves, store partial ----
        if (tid < 256) {
            float s = po_lds[tid >> 6][tid & 63] + po_lds[4 + (tid >> 6)][tid & 63];
            partial[(bn1 * 16 + n2) * 256 + tid] = s;
        }
    }
}

__global__ void reduce_mean(const float* __restrict__ partial,
                            float* __restrict__ out) {
    int e = blockIdx.x * 256 + threadIdx.x;  // (b*16+n1)*256+o
    int bn1 = e >> 8, o = e & 255;
    float s = 0.f;
#pragma unroll
    for (int n2 = 0; n2 < 16; ++n2)
        s += partial[(bn1 * 16 + n2) * 256 + o];
    out[e] = s * (1.0f / 1024.0f);
}

extern "C" void kernel_launch(void* const* d_in, const int* in_sizes, int n_in,
                              void* d_out, int out_size, void* d_ws, size_t ws_size,
                              hipStream_t stream) {
    const float* enc = (const float*)d_in[0];
    const float* W1  = (const float*)d_in[1];
    const float* W2  = (const float*)d_in[2];
    const float* W3  = (const float*)d_in[3];
    float* ws  = (float*)d_ws;
    float* out = (float*)d_out;

    const f16* W2h = (const f16*)(ws + 65536);
    const f16* W2l = (const f16*)(ws + 98304);
    const f16* W3h = (const f16*)(ws + 131072);
    const f16* W3l = (const f16*)(ws + 163840);
    float* A1   = ws + 196608;
    float* B1   = ws + 720896;
    float* part = ws + 1245184;

    prep_w<<<256, 256, 0, stream>>>(W1, W2, W3, ws);
    prep_ab<<<2048, 256, 0, stream>>>(enc, ws, A1, B1);
    relnet_main<<<dim3(2, 16, 16), 512, 0, stream>>>(A1, B1, W2h, W2l, W3h, W3l, part);
    reduce_mean<<<256, 256, 0, stream>>>(part, out);
}

// Round 8
// 336.814 us; speedup vs baseline: 2.8508x; 2.8508x over previous
//
#include <hip/hip_runtime.h>

// RelationNet: B=16, N=16, K=8, H=128, 2H=256
// out[b,n1,o] = mean over (n2,k1,k2) of relu(W3 relu(W2 relu(A[b,n1,k1]+Bv[b,n2,k2])))
// A = enc @ W1[:, :128]^T, Bv = enc @ W1[:, 128:]^T  (layer 1 factors).
// Numerics (validated R5/R7, absmax 3.9e-3): x=fp16 RN, W=fp16 hi+lo, 2 MFMA/product.
// R8 structure: 2048 short blocks (b,n1,n2-pair) x 512 thr (8 waves x 32 cols).
//   W frags in REGISTERS (loaded once/layer, zero loads in k-loop).
//   Layer-2 A-frags built IN REGISTERS from L1-hot A1/B1 (no LDS, no barrier).
//   Only o2 crosses LDS (D-frag -> A-frag), 2 barriers/block total.

typedef _Float16 f16;
typedef __attribute__((ext_vector_type(8))) _Float16 f16x8;
typedef __attribute__((ext_vector_type(4))) float    f32x4;

#define STRH 264   // o2 LDS row stride (f16): 528B, 16B-aligned rows, R3-proven

// ws layout in floats:
//   [0)        W1aT  128*256 fp32     [32768) W1bT 128*256 fp32
//   [65536)    W2h   256*256 fp16     [98304) W2l
//   [131072)   W3h   256*256 fp16     [163840) W3l
//   [196608)   A1    2048*256 fp32    [720896) B1 2048*256 fp32
//   [1245184)  partial 4096*256 fp32

__global__ void prep_w(const float* __restrict__ W1,
                       const float* __restrict__ W2,
                       const float* __restrict__ W3,
                       float* __restrict__ ws) {
    int e = blockIdx.x * 256 + threadIdx.x;   // 0..65535
    int hi = e >> 8;
    int o  = e & 255;
    if (e < 32768) {
        ws[e]         = W1[o * 256 + hi];        // W1aT[h][o]
        ws[32768 + e] = W1[o * 256 + 128 + hi];  // W1bT[h][o]
    }
    f16* W2h = (f16*)(ws + 65536);
    f16* W2l = (f16*)(ws + 98304);
    f16* W3h = (f16*)(ws + 131072);
    f16* W3l = (f16*)(ws + 163840);
    float w2 = W2[e];
    f16 h2 = (f16)w2;
    W2h[e] = h2;
    W2l[e] = (f16)(w2 - (float)h2);
    float w3 = W3[e];
    f16 h3 = (f16)w3;
    W3h[e] = h3;
    W3l[e] = (f16)(w3 - (float)h3);
}

__global__ void prep_ab(const float* __restrict__ enc,
                        const float* __restrict__ ws,
                        float* __restrict__ A1,
                        float* __restrict__ B1) {
    __shared__ float es[128];
    int row = blockIdx.x;       // 0..2047 = (b*16+n)*8+k
    int o = threadIdx.x;        // 0..255
    if (o < 128) es[o] = enc[row * 128 + o];
    __syncthreads();
    const float* __restrict__ W1aT = ws;
    const float* __restrict__ W1bT = ws + 32768;
    float a = 0.f, bv = 0.f;
#pragma unroll 8
    for (int h = 0; h < 128; ++h) {
        float ev = es[h];
        a  += ev * W1aT[h * 256 + o];
        bv += ev * W1bT[h * 256 + o];
    }
    A1[row * 256 + o] = a;
    B1[row * 256 + o] = bv;
}

__global__ __launch_bounds__(512, 2)
void relnet_main(const float* __restrict__ A1, const float* __restrict__ B1,
                 const f16* __restrict__ W2h, const f16* __restrict__ W2l,
                 const f16* __restrict__ W3h, const f16* __restrict__ W3l,
                 float* __restrict__ partial) {
    __shared__ alignas(16) f16 o2[128][STRH];   // 67.6 KB

    const int n2p = blockIdx.x;   // 0..7: pair of n2 values
    const int n1  = blockIdx.y, b = blockIdx.z;
    const int tid  = threadIdx.x;
    const int lane = tid & 63;
    const int w    = tid >> 6;     // wave 0..7 -> 32-col slice
    const int lr   = lane & 15;    // frag row (A) / col (B,D)
    const int lg   = lane >> 4;    // k-group (A/B) / row-group (D)
    const int ko   = lg * 8;
    const int cb   = w * 32;

    const int bn1 = b * 16 + n1;
    const float* __restrict__ Arow = A1 + bn1 * 8 * 256;               // 8 k1-rows
    const float* __restrict__ Brow = B1 + (b * 16 + n2p * 2) * 8 * 256; // 2 n2 x 8 k2

    // ---- W2 fragments -> registers (32 frags = 128 VGPR), reused all k-loop ----
    f16x8 wr[2][2][8];   // [cf][h/l][kt], all static indexing
#pragma unroll
    for (int cf = 0; cf < 2; ++cf) {
        const int col = cb + cf * 16 + lr;
#pragma unroll
        for (int kt = 0; kt < 8; ++kt) {
            wr[cf][0][kt] = *(const f16x8*)&W2h[col * 256 + kt * 32 + ko];
            wr[cf][1][kt] = *(const f16x8*)&W2l[col * 256 + kt * 32 + ko];
        }
    }

    f32x4 acc[8][2];
#pragma unroll
    for (int fm = 0; fm < 8; ++fm)
#pragma unroll
        for (int cf = 0; cf < 2; ++cf) acc[fm][cf] = (f32x4){0.f, 0.f, 0.f, 0.f};

    // ================= layer 2: in-register A-frag build + MFMA =================
#pragma unroll
    for (int kt = 0; kt < 8; ++kt) {
#pragma unroll
        for (int fm = 0; fm < 8; ++fm) {
            // global row = fm*16+lr: n2i=fm>>2, k1=(fm&3)*2+(lr>>3), k2=lr&7
            const int n2i = fm >> 2;
            const int k1  = (fm & 3) * 2 + (lr >> 3);
            const int k2  = lr & 7;
            const float* ap = &Arow[k1 * 256 + kt * 32 + ko];
            const float* bp = &Brow[(n2i * 8 + k2) * 256 + kt * 32 + ko];
            float4 a0 = *(const float4*)&ap[0];
            float4 a1 = *(const float4*)&ap[4];
            float4 b0 = *(const float4*)&bp[0];
            float4 b1 = *(const float4*)&bp[4];
            f16x8 x;
            x[0] = (f16)fmaxf(a0.x + b0.x, 0.f);
            x[1] = (f16)fmaxf(a0.y + b0.y, 0.f);
            x[2] = (f16)fmaxf(a0.z + b0.z, 0.f);
            x[3] = (f16)fmaxf(a0.w + b0.w, 0.f);
            x[4] = (f16)fmaxf(a1.x + b1.x, 0.f);
            x[5] = (f16)fmaxf(a1.y + b1.y, 0.f);
            x[6] = (f16)fmaxf(a1.z + b1.z, 0.f);
            x[7] = (f16)fmaxf(a1.w + b1.w, 0.f);
#pragma unroll
            for (int cf = 0; cf < 2; ++cf) {
                acc[fm][cf] = __builtin_amdgcn_mfma_f32_16x16x32_f16(x, wr[cf][0][kt], acc[fm][cf], 0, 0, 0);
                acc[fm][cf] = __builtin_amdgcn_mfma_f32_16x16x32_f16(x, wr[cf][1][kt], acc[fm][cf], 0, 0, 0);
            }
        }
    }

    // ---- issue W3 loads now (latency hidden under o2 writeback + barrier) ----
#pragma unroll
    for (int cf = 0; cf < 2; ++cf) {
        const int col = cb + cf * 16 + lr;
#pragma unroll
        for (int kt = 0; kt < 8; ++kt) {
            wr[cf][0][kt] = *(const f16x8*)&W3h[col * 256 + kt * 32 + ko];
            wr[cf][1][kt] = *(const f16x8*)&W3l[col * 256 + kt * 32 + ko];
        }
    }

    // ---- o2 = fp16(relu(acc)) -> LDS (D-frag: col=lr, row=lg*4+j) ----
#pragma unroll
    for (int fm = 0; fm < 8; ++fm)
#pragma unroll
        for (int cf = 0; cf < 2; ++cf)
#pragma unroll
            for (int j = 0; j < 4; ++j) {
                float v = fmaxf(acc[fm][cf][j], 0.f);
                o2[fm * 16 + lg * 4 + j][cb + cf * 16 + lr] = (f16)v;
            }
    __syncthreads();

    // ================= layer 3: A-frags from LDS, W3 in regs =================
#pragma unroll
    for (int fm = 0; fm < 8; ++fm)
#pragma unroll
        for (int cf = 0; cf < 2; ++cf) acc[fm][cf] = (f32x4){0.f, 0.f, 0.f, 0.f};

#pragma unroll
    for (int kt = 0; kt < 8; ++kt) {
#pragma unroll
        for (int fm = 0; fm < 8; ++fm) {
            f16x8 x = *(const f16x8*)&o2[fm * 16 + lr][kt * 32 + ko];
#pragma unroll
            for (int cf = 0; cf < 2; ++cf) {
                acc[fm][cf] = __builtin_amdgcn_mfma_f32_16x16x32_f16(x, wr[cf][0][kt], acc[fm][cf], 0, 0, 0);
                acc[fm][cf] = __builtin_amdgcn_mfma_f32_16x16x32_f16(x, wr[cf][1][kt], acc[fm][cf], 0, 0, 0);
            }
        }
    }

    // ---- relu + row-sum per n2-group (rows 0..63 -> n2p*2, 64..127 -> +1) ----
    float po[2][2] = {{0.f, 0.f}, {0.f, 0.f}};
#pragma unroll
    for (int fm = 0; fm < 8; ++fm) {
        const int g = fm >> 2;
#pragma unroll
        for (int cf = 0; cf < 2; ++cf)
#pragma unroll
            for (int j = 0; j < 4; ++j)
                po[g][cf] += fmaxf(acc[fm][cf][j], 0.f);
    }
#pragma unroll
    for (int g = 0; g < 2; ++g)
#pragma unroll
        for (int cf = 0; cf < 2; ++cf) {
            po[g][cf] += __shfl_xor(po[g][cf], 16);
            po[g][cf] += __shfl_xor(po[g][cf], 32);
        }
    if (lane < 16) {
#pragma unroll
        for (int g = 0; g < 2; ++g) {
            float* pb = partial + ((bn1 * 16 + n2p * 2 + g) * 256) + cb + lr;
            pb[0]  = po[g][0];
            pb[16] = po[g][1];
        }
    }
}

__global__ void reduce_mean(const float* __restrict__ partial,
                            float* __restrict__ out) {
    int e = blockIdx.x * 256 + threadIdx.x;  // (b*16+n1)*256+o
    int bn1 = e >> 8, o = e & 255;
    float s = 0.f;
#pragma unroll
    for (int n2 = 0; n2 < 16; ++n2)
        s += partial[(bn1 * 16 + n2) * 256 + o];
    out[e] = s * (1.0f / 1024.0f);
}

extern "C" void kernel_launch(void* const* d_in, const int* in_sizes, int n_in,
                              void* d_out, int out_size, void* d_ws, size_t ws_size,
                              hipStream_t stream) {
    const float* enc = (const float*)d_in[0];
    const float* W1  = (const float*)d_in[1];
    const float* W2  = (const float*)d_in[2];
    const float* W3  = (const float*)d_in[3];
    float* ws  = (float*)d_ws;
    float* out = (float*)d_out;

    const f16* W2h = (const f16*)(ws + 65536);
    const f16* W2l = (const f16*)(ws + 98304);
    const f16* W3h = (const f16*)(ws + 131072);
    const f16* W3l = (const f16*)(ws + 163840);
    float* A1   = ws + 196608;
    float* B1   = ws + 720896;
    float* part = ws + 1245184;

    prep_w<<<256, 256, 0, stream>>>(W1, W2, W3, ws);
    prep_ab<<<2048, 256, 0, stream>>>(enc, ws, A1, B1);
    relnet_main<<<dim3(8, 16, 16), 512, 0, stream>>>(A1, B1, W2h, W2l, W3h, W3l, part);
    reduce_mean<<<256, 256, 0, stream>>>(part, out);
}

// Round 9
// 289.160 us; speedup vs baseline: 3.3206x; 1.1648x over previous
//
#include <hip/hip_runtime.h>

// RelationNet: B=16, N=16, K=8, H=128, 2H=256
// out[b,n1,o] = mean over (n2,k1,k2) of relu(W3 relu(W2 relu(A[b,n1,k1]+Bv[b,n2,k2])))
// A = enc @ W1[:, :128]^T, Bv = enc @ W1[:, 128:]^T  (layer 1 factors).
// Numerics (validated R5/R7/R8, absmax 3.9e-3): x=fp16 RN, W=fp16 hi+lo, 2 MFMA/product.
// R9: swapped-operand MFMA  D[o][r] = mfma(A=W, B=x)  ->
//   - x-frags fed from LDS (1 ds_read_b128 per 4 MFMA, no in-loop addr VALU)
//   - o2 writeback as b64 into transposed o2t[r][o]
//   - XOR swizzle f ^= ((r>>3)&3)<<4 on both LDS buffers -> 2-way banks (free)
//   - W frags in registers (loaded once/layer), 2 barriers/block

typedef _Float16 f16;
typedef __attribute__((ext_vector_type(4))) _Float16 f16x4;
typedef __attribute__((ext_vector_type(8))) _Float16 f16x8;
typedef __attribute__((ext_vector_type(4))) float    f32x4;

#define STRH 264
#define SWZ(r, f) ((f) ^ ((((r) >> 3) & 3) << 4))

// ws layout in floats:
//   [0)        W1aT  128*256 fp32     [32768) W1bT 128*256 fp32
//   [65536)    W2h   256*256 fp16     [98304) W2l
//   [131072)   W3h   256*256 fp16     [163840) W3l
//   [196608)   A1    2048*256 fp32    [720896) B1 2048*256 fp32
//   [1245184)  partial 4096*256 fp32

__global__ void prep_w(const float* __restrict__ W1,
                       const float* __restrict__ W2,
                       const float* __restrict__ W3,
                       float* __restrict__ ws) {
    int e = blockIdx.x * 256 + threadIdx.x;   // 0..65535
    int hi = e >> 8;
    int o  = e & 255;
    if (e < 32768) {
        ws[e]         = W1[o * 256 + hi];        // W1aT[h][o]
        ws[32768 + e] = W1[o * 256 + 128 + hi];  // W1bT[h][o]
    }
    f16* W2h = (f16*)(ws + 65536);
    f16* W2l = (f16*)(ws + 98304);
    f16* W3h = (f16*)(ws + 131072);
    f16* W3l = (f16*)(ws + 163840);
    float w2 = W2[e];
    f16 h2 = (f16)w2;
    W2h[e] = h2;
    W2l[e] = (f16)(w2 - (float)h2);
    float w3 = W3[e];
    f16 h3 = (f16)w3;
    W3h[e] = h3;
    W3l[e] = (f16)(w3 - (float)h3);
}

__global__ void prep_ab(const float* __restrict__ enc,
                        const float* __restrict__ ws,
                        float* __restrict__ A1,
                        float* __restrict__ B1) {
    __shared__ float es[128];
    int row = blockIdx.x;       // 0..2047 = (b*16+n)*8+k
    int o = threadIdx.x;        // 0..255
    if (o < 128) es[o] = enc[row * 128 + o];
    __syncthreads();
    const float* __restrict__ W1aT = ws;
    const float* __restrict__ W1bT = ws + 32768;
    float a = 0.f, bv = 0.f;
#pragma unroll 8
    for (int h = 0; h < 128; ++h) {
        float ev = es[h];
        a  += ev * W1aT[h * 256 + o];
        bv += ev * W1bT[h * 256 + o];
    }
    A1[row * 256 + o] = a;
    B1[row * 256 + o] = bv;
}

__global__ __launch_bounds__(512, 2)
void relnet_main(const float* __restrict__ A1, const float* __restrict__ B1,
                 const f16* __restrict__ W2h, const f16* __restrict__ W2l,
                 const f16* __restrict__ W3h, const f16* __restrict__ W3l,
                 float* __restrict__ partial) {
    __shared__ alignas(16) f16 o1 [128][STRH];   // 66 KB, x1 (layer-2 input)
    __shared__ alignas(16) f16 o2t[128][STRH];   // 66 KB, x2 transposed [r][o]

    const int n2p = blockIdx.x;   // 0..7: pair of n2 values
    const int n1  = blockIdx.y, b = blockIdx.z;
    const int tid  = threadIdx.x;
    const int lane = tid & 63;
    const int w    = tid >> 6;     // wave 0..7 -> 32-col (o) slice
    const int lr   = lane & 15;    // A row (=o) / B col (=r) / D col (=r)
    const int lg   = lane >> 4;    // k-group; D row-group
    const int ko   = lg * 8;
    const int cb   = w * 32;

    const int bn1 = b * 16 + n1;

    // ---- build o1[128][256] = fp16(relu(A[k1]+Bv[k2])) into LDS ----
    {
        const int r = (w & 1) * 64 + lane;   // row 0..127 (unique with g)
        const int g = w >> 1;                // 64-col chunk 0..3
        const int k1 = (r >> 3) & 7, k2 = r & 7;
        const float* __restrict__ ap = A1 + (bn1 * 8 + k1) * 256 + g * 64;
        const float* __restrict__ bp = B1 + ((b * 16 + n2p * 2 + (r >> 6)) * 8 + k2) * 256 + g * 64;
#pragma unroll
        for (int i = 0; i < 8; ++i) {
            float4 a0 = *(const float4*)&ap[i * 8];
            float4 a1 = *(const float4*)&ap[i * 8 + 4];
            float4 b0 = *(const float4*)&bp[i * 8];
            float4 b1 = *(const float4*)&bp[i * 8 + 4];
            f16x8 x;
            x[0] = (f16)fmaxf(a0.x + b0.x, 0.f);
            x[1] = (f16)fmaxf(a0.y + b0.y, 0.f);
            x[2] = (f16)fmaxf(a0.z + b0.z, 0.f);
            x[3] = (f16)fmaxf(a0.w + b0.w, 0.f);
            x[4] = (f16)fmaxf(a1.x + b1.x, 0.f);
            x[5] = (f16)fmaxf(a1.y + b1.y, 0.f);
            x[6] = (f16)fmaxf(a1.z + b1.z, 0.f);
            x[7] = (f16)fmaxf(a1.w + b1.w, 0.f);
            *(f16x8*)&o1[r][SWZ(r, g * 64 + i * 8)] = x;
        }
    }

    // ---- W2 fragments -> registers (A-operand: row=o=lane&15, same addrs) ----
    f16x8 wr[2][2][8];   // [cf][hi/lo][kt]
#pragma unroll
    for (int cf = 0; cf < 2; ++cf) {
        const int col = cb + cf * 16 + lr;
#pragma unroll
        for (int kt = 0; kt < 8; ++kt) {
            wr[cf][0][kt] = *(const f16x8*)&W2h[col * 256 + kt * 32 + ko];
            wr[cf][1][kt] = *(const f16x8*)&W2l[col * 256 + kt * 32 + ko];
        }
    }

    f32x4 acc[8][2];
#pragma unroll
    for (int fm = 0; fm < 8; ++fm)
#pragma unroll
        for (int cf = 0; cf < 2; ++cf) acc[fm][cf] = (f32x4){0.f, 0.f, 0.f, 0.f};

    __syncthreads();   // o1 ready

    // ================= layer 2: D[o][r] += W2 * x1 =================
#pragma unroll
    for (int kt = 0; kt < 8; ++kt) {
        f16x8 x[8];
#pragma unroll
        for (int fm = 0; fm < 8; ++fm) {
            const int rr = fm * 16 + lr;
            x[fm] = *(const f16x8*)&o1[rr][SWZ(rr, kt * 32 + ko)];
        }
#pragma unroll
        for (int fm = 0; fm < 8; ++fm)
#pragma unroll
            for (int cf = 0; cf < 2; ++cf) {
                acc[fm][cf] = __builtin_amdgcn_mfma_f32_16x16x32_f16(wr[cf][0][kt], x[fm], acc[fm][cf], 0, 0, 0);
                acc[fm][cf] = __builtin_amdgcn_mfma_f32_16x16x32_f16(wr[cf][1][kt], x[fm], acc[fm][cf], 0, 0, 0);
            }
    }

    // ---- issue W3 loads (latency hidden under o2t writeback + barrier) ----
#pragma unroll
    for (int cf = 0; cf < 2; ++cf) {
        const int col = cb + cf * 16 + lr;
#pragma unroll
        for (int kt = 0; kt < 8; ++kt) {
            wr[cf][0][kt] = *(const f16x8*)&W3h[col * 256 + kt * 32 + ko];
            wr[cf][1][kt] = *(const f16x8*)&W3l[col * 256 + kt * 32 + ko];
        }
    }

    // ---- o2t[r][o] = fp16(relu(acc)): b64 stores (4 consecutive o) ----
#pragma unroll
    for (int fm = 0; fm < 8; ++fm) {
        const int rr = fm * 16 + lr;
#pragma unroll
        for (int cf = 0; cf < 2; ++cf) {
            f16x4 v;
#pragma unroll
            for (int j = 0; j < 4; ++j) v[j] = (f16)fmaxf(acc[fm][cf][j], 0.f);
            *(f16x4*)&o2t[rr][SWZ(rr, cb + cf * 16 + lg * 4)] = v;
        }
    }
    __syncthreads();   // o2t ready

    // ================= layer 3: D[o][r] += W3 * x2 =================
#pragma unroll
    for (int fm = 0; fm < 8; ++fm)
#pragma unroll
        for (int cf = 0; cf < 2; ++cf) acc[fm][cf] = (f32x4){0.f, 0.f, 0.f, 0.f};

#pragma unroll
    for (int kt = 0; kt < 8; ++kt) {
        f16x8 x[8];
#pragma unroll
        for (int fm = 0; fm < 8; ++fm) {
            const int rr = fm * 16 + lr;
            x[fm] = *(const f16x8*)&o2t[rr][SWZ(rr, kt * 32 + ko)];
        }
#pragma unroll
        for (int fm = 0; fm < 8; ++fm)
#pragma unroll
            for (int cf = 0; cf < 2; ++cf) {
                acc[fm][cf] = __builtin_amdgcn_mfma_f32_16x16x32_f16(wr[cf][0][kt], x[fm], acc[fm][cf], 0, 0, 0);
                acc[fm][cf] = __builtin_amdgcn_mfma_f32_16x16x32_f16(wr[cf][1][kt], x[fm], acc[fm][cf], 0, 0, 0);
            }
    }

    // ---- relu + sum over r: fm within n2-group, then lr lanes (bits 0..3) ----
    float po[2][2][4];
#pragma unroll
    for (int g = 0; g < 2; ++g)
#pragma unroll
        for (int cf = 0; cf < 2; ++cf)
#pragma unroll
            for (int j = 0; j < 4; ++j) po[g][cf][j] = 0.f;
#pragma unroll
    for (int fm = 0; fm < 8; ++fm) {
        const int g = fm >> 2;
#pragma unroll
        for (int cf = 0; cf < 2; ++cf)
#pragma unroll
            for (int j = 0; j < 4; ++j)
                po[g][cf][j] += fmaxf(acc[fm][cf][j], 0.f);
    }
#pragma unroll
    for (int g = 0; g < 2; ++g)
#pragma unroll
        for (int cf = 0; cf < 2; ++cf)
#pragma unroll
            for (int j = 0; j < 4; ++j) {
                po[g][cf][j] += __shfl_xor(po[g][cf][j], 1);
                po[g][cf][j] += __shfl_xor(po[g][cf][j], 2);
                po[g][cf][j] += __shfl_xor(po[g][cf][j], 4);
                po[g][cf][j] += __shfl_xor(po[g][cf][j], 8);
            }
    if (lr == 0) {
#pragma unroll
        for (int g = 0; g < 2; ++g) {
            float* pb = partial + ((bn1 * 16 + n2p * 2 + g) * 256) + cb + lg * 4;
#pragma unroll
            for (int cf = 0; cf < 2; ++cf)
                *(float4*)&pb[cf * 16] =
                    make_float4(po[g][cf][0], po[g][cf][1], po[g][cf][2], po[g][cf][3]);
        }
    }
}

__global__ void reduce_mean(const float* __restrict__ partial,
                            float* __restrict__ out) {
    int e = blockIdx.x * 256 + threadIdx.x;  // (b*16+n1)*256+o
    int bn1 = e >> 8, o = e & 255;
    float s = 0.f;
#pragma unroll
    for (int n2 = 0; n2 < 16; ++n2)
        s += partial[(bn1 * 16 + n2) * 256 + o];
    out[e] = s * (1.0f / 1024.0f);
}

extern "C" void kernel_launch(void* const* d_in, const int* in_sizes, int n_in,
                              void* d_out, int out_size, void* d_ws, size_t ws_size,
                              hipStream_t stream) {
    const float* enc = (const float*)d_in[0];
    const float* W1  = (const float*)d_in[1];
    const float* W2  = (const float*)d_in[2];
    const float* W3  = (const float*)d_in[3];
    float* ws  = (float*)d_ws;
    float* out = (float*)d_out;

    const f16* W2h = (const f16*)(ws + 65536);
    const f16* W2l = (const f16*)(ws + 98304);
    const f16* W3h = (const f16*)(ws + 131072);
    const f16* W3l = (const f16*)(ws + 163840);
    float* A1   = ws + 196608;
    float* B1   = ws + 720896;
    float* part = ws + 1245184;

    prep_w<<<256, 256, 0, stream>>>(W1, W2, W3, ws);
    prep_ab<<<2048, 256, 0, stream>>>(enc, ws, A1, B1);
    relnet_main<<<dim3(8, 16, 16), 512, 0, stream>>>(A1, B1, W2h, W2l, W3h, W3l, part);
    reduce_mean<<<256, 256, 0, stream>>>(part, out);
}